// Round 3
// baseline (236.343 us; speedup 1.0000x reference)
//
#include <hip/hip_runtime.h>

// roll(cache, -64, axis=1) then last 64 rows := x.
// B=4, S=8192, D=1024, n=64, fp32.
// Flat float4 view: D4 = 256 float4/row, SHIFT4 = 64*1024/4 = 16384.
// For s < S-n: out[idx] = cache[idx + SHIFT4]  (flat shift stays within batch b)
// For s >= S-n: out[idx] = x[(b*64 + (s-(S-n)))*256 + d4]
//
// Pure streaming op: grid-stride with 2048 blocks (256 CU x 8 wg),
// 16B/lane vector ops, non-temporal load/store to bypass cache pollution.
// Use clang ext_vector_type (not HIP_vector_type) so the nontemporal
// builtins accept the pointer.

typedef float f32x4 __attribute__((ext_vector_type(4)));

__global__ __launch_bounds__(256) void roll_set_kernel(
    const f32x4* __restrict__ x4,
    const f32x4* __restrict__ cache4,
    f32x4* __restrict__ out4,
    int total4) {
    const int D4     = 256;    // 1024 / 4
    const int S      = 8192;
    const int n      = 64;
    const int SHIFT4 = n * D4; // 16384

    int stride = gridDim.x * blockDim.x;
    for (int idx = blockIdx.x * blockDim.x + threadIdx.x; idx < total4;
         idx += stride) {
        int row = idx >> 8;        // idx / D4
        int s   = row & (S - 1);   // row % S
        f32x4 v;
        if (s < S - n) {
            // bulk: flat-shifted copy (branch is wave-uniform: 64 lanes share a row)
            v = __builtin_nontemporal_load(&cache4[idx + SHIFT4]);
        } else {
            int b = row >> 13;     // row / S
            int i = s - (S - n);   // 0..63
            v = x4[(b * n + i) * D4 + (idx & (D4 - 1))];
        }
        __builtin_nontemporal_store(v, &out4[idx]);
    }
}

extern "C" void kernel_launch(void* const* d_in, const int* in_sizes, int n_in,
                              void* d_out, int out_size, void* d_ws, size_t ws_size,
                              hipStream_t stream) {
    const float* x     = (const float*)d_in[0];   // [4, 64, 1024] fp32
    const float* cache = (const float*)d_in[1];   // [4, 8192, 1024] fp32
    float* out         = (float*)d_out;           // [4, 8192, 1024] fp32

    int total4  = out_size / 4;                   // 8,388,608 float4
    int threads = 256;
    int blocks  = 2048;                           // 256 CUs x 8 workgroups

    roll_set_kernel<<<blocks, threads, 0, stream>>>(
        (const f32x4*)x, (const f32x4*)cache, (f32x4*)out, total4);
}